// Round 8
// baseline (234.640 us; speedup 1.0000x reference)
//
#include <hip/hip_runtime.h>
#include <hip/hip_bf16.h>

#define N_NODES 25000
#define N_EDGES 100000
#define E_PAD   100096   // 782 * 128

typedef __attribute__((ext_vector_type(8))) short bf16x8;
typedef __attribute__((ext_vector_type(4))) float f32x4;
typedef __attribute__((ext_vector_type(4))) unsigned short u16x4;

__device__ __forceinline__ void gload_lds16(const void* g, void* l) {
  __builtin_amdgcn_global_load_lds(
      (const __attribute__((address_space(1))) unsigned int*)g,
      (__attribute__((address_space(3))) unsigned int*)l, 16, 0, 0);
}

__device__ __forceinline__ unsigned short f2bf(float v) {
  __hip_bfloat16 hb = __float2bfloat16(v);
  return *reinterpret_cast<unsigned short*>(&hb);
}
__device__ __forceinline__ float bf2f(unsigned short u) {
  return __uint_as_float(((unsigned)u) << 16);
}

__device__ __forceinline__ unsigned fkey(float f) {
  unsigned u = __float_as_uint(f);
  return (u & 0x80000000u) ? ~u : (u | 0x80000000u);
}
__device__ __forceinline__ float fdec(unsigned k) {
  return (k & 0x80000000u) ? __uint_as_float(k ^ 0x80000000u) : __uint_as_float(~k);
}

// h = relu(e @ W1 + b1), bf16, in per-128-edge-block MFMA A-fragment order:
// frag f = b*32 + g16*4 + s (g16 = 16-edge group 0..7, s = K-step 0..3), lane:
// holds h[b*128 + g16*16 + (lane&15)][s*32 + (lane>>4)*8 .. +8], stored at g*16.
__global__ __launch_bounds__(256) void k_h(const float* __restrict__ ef,
    const float* __restrict__ W1, const float* __restrict__ b1,
    unsigned char* __restrict__ hfr) {
  int g = blockIdx.x * 256 + threadIdx.x;          // E_PAD*16 threads
  int lane = g & 63, f = g >> 6;
  int s = f & 3, g16 = (f >> 2) & 7, b = f >> 5;
  int e = b * 128 + g16 * 16 + (lane & 15);
  int k0 = s * 32 + ((lane >> 4) & 3) * 8;
  bf16x8 v;
  if (e < N_EDGES) {
    f32x4 acc0 = *(const f32x4*)(b1 + k0);
    f32x4 acc1 = *(const f32x4*)(b1 + k0 + 4);
    const float* er = ef + (size_t)e * 16;
    #pragma unroll
    for (int j = 0; j < 16; ++j) {
      float ev = er[j];
      f32x4 w0 = *(const f32x4*)(W1 + j * 128 + k0);
      f32x4 w1 = *(const f32x4*)(W1 + j * 128 + k0 + 4);
      #pragma unroll
      for (int r = 0; r < 4; ++r) { acc0[r] += ev * w0[r]; acc1[r] += ev * w1[r]; }
    }
    #pragma unroll
    for (int r = 0; r < 4; ++r) {
      v[r]     = (short)f2bf(acc0[r] > 0.f ? acc0[r] : 0.f);
      v[r + 4] = (short)f2bf(acc1[r] > 0.f ? acc1[r] : 0.f);
    }
  } else {
    #pragma unroll
    for (int r = 0; r < 8; ++r) v[r] = 0;
  }
  *(bf16x8*)(hfr + (size_t)g * 16) = v;
}

// W2 -> bf16 B-fragments, PRE-SWIZZLED for conflict-reduced LDS reads:
// frag (chunk i, col-group c2, lane, s) at ((i*4+c2)*64+lane)*64 + (s*16 ^ ((lane&3)<<4))
// holds W2[s*32+(lane>>4)*8 .. +8][i*64 + c2*16 + (lane&15)].
// R7 BUG FIX: col was missing the i*64 chunk offset.
__global__ __launch_bounds__(256) void k_w2pk(const float* __restrict__ W2,
    unsigned char* __restrict__ out) {
  int g = blockIdx.x * 256 + threadIdx.x;          // 32768 threads
  int s = g & 3, lane = (g >> 2) & 63, c2 = (g >> 8) & 3, i = g >> 10;
  int col = i * 64 + c2 * 16 + (lane & 15);
  int k0 = s * 32 + (lane >> 4) * 8;
  bf16x8 v;
  #pragma unroll
  for (int j = 0; j < 8; ++j)
    v[j] = (short)f2bf(W2[(size_t)(k0 + j) * 2048 + col]);
  size_t base = ((size_t)(i * 4 + c2) * 64 + lane) * 64;
  *(bf16x8*)(out + base + ((s * 16) ^ ((lane & 3) << 4))) = v;
}

// Fused node-side prep: out = bias + x@root; xb = x@b2' ; ab1/ab2 ; mk/s init.
__global__ __launch_bounds__(256) void k_pre(const float* __restrict__ x,
    const float* __restrict__ root, const float* __restrict__ b2,
    const float* __restrict__ att, const float* __restrict__ bias,
    float* __restrict__ out, float* __restrict__ xb,
    float* __restrict__ ab1, float* __restrict__ ab2,
    unsigned* __restrict__ mk, float* __restrict__ s_sum) {
  __shared__ float lxb[4][64];
  int g = blockIdx.x * 256 + threadIdx.x;          // N*64 exact
  int n = g >> 6, o = g & 63;
  const float* xr = x + (size_t)n * 32;
  float ra = bias[o], xa = 0.f;
  #pragma unroll
  for (int i = 0; i < 32; ++i) {
    float xv = xr[i];
    ra += xv * root[i * 64 + o];
    xa += xv * b2[i * 64 + o];
  }
  out[g] = ra;
  xb[g] = xa;
  int ln = threadIdx.x >> 6;
  lxb[ln][o] = xa;
  __syncthreads();
  if (o < 8) {
    int hd = o;
    float s1 = 0.f, s2 = 0.f;
    #pragma unroll
    for (int c = 0; c < 8; ++c) {
      float v = lxb[ln][hd * 8 + c];
      s1 += v * att[hd * 16 + c];
      s2 += v * att[hd * 16 + 8 + c];
    }
    size_t idx = (size_t)n * 8 + hd;
    ab1[idx] = s1; ab2[idx] = s2; mk[idx] = 0u; s_sum[idx] = 0.f;
  }
}

// Block = 128 edges, 4 waves, wave-tile = 64 edges x 32 cols (mt=4, nt=2).
// acc = 64 VGPR (unspillable). A-frags (16) loaded once from global
// fragment-ordered h, pinned (LDS 48K caps occupancy at 3 blocks/CU, so the
// allocator has no incentive to spill them). W2 chunk double-buffered in LDS
// (one barrier/chunk, pre-swizzled). xs/xd bf16 in LDS.
__global__ __launch_bounds__(256)
__attribute__((amdgpu_waves_per_eu(2)))
void k_main(
    const float* __restrict__ x, const int* __restrict__ ei,
    const float* __restrict__ att, const float* __restrict__ ab1,
    const float* __restrict__ ab2, const unsigned char* __restrict__ hfr,
    const unsigned char* __restrict__ w2pk,
    float* __restrict__ xj_out, float* __restrict__ alpha_out,
    unsigned* __restrict__ mk) {
  __shared__ unsigned char lds_b[2][16384];        // W2 chunk double buffer
  __shared__ unsigned short lds_x[2][32][128];     // [xs/xd][ch][edge] bf16
  const int tid = threadIdx.x;
  const int lane = tid & 63;
  const int w = tid >> 6;
  const int eh = w >> 1;                           // edge-half: rows eh*64..+64
  const int ch = w & 1;                            // col-half: cols ch*32..+32
  const int e0 = blockIdx.x * 128;
  const int* srcp = ei;
  const int* dstp = ei + N_EDGES;

  // A fragments: 16 coalesced dwordx4, once, pinned.
  const unsigned char* hp = hfr + (size_t)blockIdx.x * 32768;
  bf16x8 af[4][4];
  #pragma unroll
  for (int mt = 0; mt < 4; ++mt)
    #pragma unroll
    for (int s = 0; s < 4; ++s)
      af[mt][s] = *(const bf16x8*)(hp + (size_t)(((eh * 4 + mt) * 4 + s) * 64 + lane) * 16);
  #pragma unroll
  for (int mt = 0; mt < 4; ++mt)
    #pragma unroll
    for (int s = 0; s < 4; ++s)
      asm volatile("" : "+v"(af[mt][s]));

  // stage W2 chunk 0 (linear copy; source pre-swizzled)
  #pragma unroll
  for (int r = 0; r < 4; ++r)
    gload_lds16(w2pk + r * 4096 + tid * 16, &lds_b[0][0] + r * 4096 + tid * 16);

  // gather x rows -> bf16 transposed LDS: thread t: which=t>>7, edge m=t&127
  {
    int which = tid >> 7, m = tid & 127;
    int eIdx = e0 + m; if (eIdx >= N_EDGES) eIdx = N_EDGES - 1;
    int node = which ? dstp[eIdx] : srcp[eIdx];
    const f32x4* xr = (const f32x4*)(x + (size_t)node * 32);
    #pragma unroll
    for (int q = 0; q < 8; ++q) {
      f32x4 vv = xr[q];
      #pragma unroll
      for (int j = 0; j < 4; ++j) lds_x[which][q * 4 + j][m] = f2bf(vv[j]);
    }
  }
  __syncthreads();

  f32x4 xj_acc[4][2] = {};
  f32x4 xi_acc[4][2] = {};
  const int rg4 = ((lane >> 4) & 3) * 4;
  const int l15 = lane & 15;
  const int rowb = eh * 64;
  const int bswz = (lane & 3) << 4;

  #pragma unroll 1
  for (int i = 0; i < 32; ++i) {
    const int cur = i & 1;
    if (i < 31) {  // stage next chunk into other buffer
      const unsigned char* wg = w2pk + (size_t)(i + 1) * 16384;
      unsigned char* lb = &lds_b[cur ^ 1][0];
      #pragma unroll
      for (int r = 0; r < 4; ++r)
        gload_lds16(wg + r * 4096 + tid * 16, lb + r * 4096 + tid * 16);
    }
    // B fragments for this wave's 2 col-groups
    const unsigned char* bb = &lds_b[cur][0];
    bf16x8 bf[2][4];
    #pragma unroll
    for (int nt = 0; nt < 2; ++nt)
      #pragma unroll
      for (int s = 0; s < 4; ++s)
        bf[nt][s] = *(const bf16x8*)(bb + ((ch * 2 + nt) * 64 + lane) * 64 + ((s * 16) ^ bswz));
    __builtin_amdgcn_s_setprio(1);
    #pragma unroll
    for (int mt = 0; mt < 4; ++mt) {
      u16x4 xsh = *(const u16x4*)&lds_x[0][i][rowb + mt * 16 + rg4];
      u16x4 xdh = *(const u16x4*)&lds_x[1][i][rowb + mt * 16 + rg4];
      #pragma unroll
      for (int nt = 0; nt < 2; ++nt) {
        f32x4 g = {0.f, 0.f, 0.f, 0.f};
        #pragma unroll
        for (int s = 0; s < 4; ++s)
          g = __builtin_amdgcn_mfma_f32_16x16x32_bf16(af[mt][s], bf[nt][s], g, 0, 0, 0);
        #pragma unroll
        for (int r = 0; r < 4; ++r) {
          xj_acc[mt][nt][r] += bf2f(xsh[r]) * g[r];
          xi_acc[mt][nt][r] += bf2f(xdh[r]) * g[r];
        }
      }
    }
    __builtin_amdgcn_s_setprio(0);
    __syncthreads();   // drains staging vmcnt; protects buffer reuse
  }

  // epilogue: xj stores, per-head logits (8-lane shuffle reduce), atomicMax
  const int cc = lane & 7;
  const int hsel = (lane >> 3) & 1;
  float a1v[2], a2v[2];
  #pragma unroll
  for (int nt = 0; nt < 2; ++nt) {
    int head = ch * 4 + nt * 2 + hsel;
    a1v[nt] = att[head * 16 + cc];
    a2v[nt] = att[head * 16 + 8 + cc];
  }
  #pragma unroll
  for (int mt = 0; mt < 4; ++mt) {
    #pragma unroll
    for (int r = 0; r < 4; ++r) {
      int row = rowb + mt * 16 + rg4 + r;
      int eIdx = e0 + row;
      #pragma unroll
      for (int nt = 0; nt < 2; ++nt) {
        int o = ch * 32 + nt * 16 + l15;
        xj_out[(size_t)eIdx * 64 + o] = xj_acc[mt][nt][r];
        float v = xi_acc[mt][nt][r] * a1v[nt] + xj_acc[mt][nt][r] * a2v[nt];
        v += __shfl_xor(v, 1);
        v += __shfl_xor(v, 2);
        v += __shfl_xor(v, 4);
        if (cc == 0 && eIdx < N_EDGES) {
          int head = ch * 4 + nt * 2 + hsel;
          int d = dstp[eIdx];
          float lg = v + ab1[(size_t)d * 8 + head] + ab2[(size_t)srcp[eIdx] * 8 + head];
          lg = lg > 0.f ? lg : 0.2f * lg;
          alpha_out[(size_t)eIdx * 8 + head] = lg;
          atomicMax(mk + (size_t)d * 8 + head, fkey(lg));
        }
      }
    }
  }
}

__global__ __launch_bounds__(256) void k_exp(float* __restrict__ alpha,
    const int* __restrict__ ei, const unsigned* __restrict__ mk, float* __restrict__ s) {
  int g = blockIdx.x * 256 + threadIdx.x;          // E*8 exact
  int e = g >> 3, hd = g & 7;
  int d = ei[N_EDGES + e];
  float ea = expf(alpha[g] - fdec(mk[(size_t)d * 8 + hd]));
  alpha[g] = ea;
  atomicAdd(s + (size_t)d * 8 + hd, ea);
}

__global__ __launch_bounds__(256) void k_scatter(const float* __restrict__ xj,
    const float* __restrict__ xb, const float* __restrict__ alpha,
    const float* __restrict__ s, const int* __restrict__ ei,
    const float* __restrict__ bias, float* __restrict__ out) {
  int g = blockIdx.x * 256 + threadIdx.x;          // E*64 exact
  int e = g >> 6, o = g & 63, hd = o >> 3;
  int sidx = ei[e], d = ei[N_EDGES + e];
  float ea = alpha[(size_t)e * 8 + hd];
  float sv = s[(size_t)d * 8 + hd];
  float val = (xj[g] + xb[(size_t)sidx * 64 + o]) * (ea / (sv + 1e-16f)) + bias[o];
  atomicAdd(out + (size_t)d * 64 + o, val);
}

__global__ __launch_bounds__(256) void k_elu(float* __restrict__ out) {
  int g = blockIdx.x * 256 + threadIdx.x;          // N*64 exact
  float v = out[g];
  out[g] = v > 0.f ? v : expm1f(v);
}

extern "C" void kernel_launch(void* const* d_in, const int* in_sizes, int n_in,
                              void* d_out, int out_size, void* d_ws, size_t ws_size,
                              hipStream_t stream) {
  const float* x    = (const float*)d_in[0];
  const int*   eidx = (const int*)d_in[1];
  const float* ef   = (const float*)d_in[2];
  const float* W1   = (const float*)d_in[3];
  const float* b1   = (const float*)d_in[4];
  const float* W2   = (const float*)d_in[5];
  const float* b2   = (const float*)d_in[6];
  const float* att  = (const float*)d_in[7];
  const float* bias = (const float*)d_in[8];
  const float* root = (const float*)d_in[9];
  float* out = (float*)d_out;
  char* ws = (char*)d_ws;

  // workspace layout (256B aligned), total ~64.6 MB
  unsigned char* h_fr  = (unsigned char*)(ws + 0);          // E_PAD*256B = 25,624,576
  unsigned char* w2pk  = (unsigned char*)(ws + 25624576);   // 512 KB
  float* xb    = (float*)(ws + 26148864);                   // N*64 f32
  float* ab1   = (float*)(ws + 32548864);                   // N*8 f32
  float* ab2   = (float*)(ws + 33348864);                   // N*8 f32
  float* xj_ws = (float*)(ws + 34148864);                   // E_PAD*64 f32
  float* al_ws = (float*)(ws + 59773440);                   // E_PAD*8 f32
  unsigned* mk = (unsigned*)(ws + 62976512);                // N*8 u32
  float* s_sum = (float*)(ws + 63776512);                   // N*8 f32

  k_h    <<<E_PAD * 16 / 256, 256, 0, stream>>>(ef, W1, b1, h_fr);
  k_w2pk <<<128, 256, 0, stream>>>(W2, w2pk);
  k_pre  <<<N_NODES * 64 / 256, 256, 0, stream>>>(x, root, b2, att, bias,
                                                  out, xb, ab1, ab2, mk, s_sum);
  k_main <<<E_PAD / 128, 256, 0, stream>>>(x, eidx, att, ab1, ab2, h_fr, w2pk,
                                           xj_ws, al_ws, mk);
  k_exp  <<<N_EDGES * 8 / 256, 256, 0, stream>>>(al_ws, eidx, mk, s_sum);
  k_scatter<<<N_EDGES * 64 / 256, 256, 0, stream>>>(xj_ws, xb, al_ws, s_sum, eidx, bias, out);
  k_elu  <<<N_NODES * 64 / 256, 256, 0, stream>>>(out);
}

// Round 9
// 209.807 us; speedup vs baseline: 1.1184x; 1.1184x over previous
//
#include <hip/hip_runtime.h>
#include <hip/hip_bf16.h>

#define N_NODES 25000
#define N_EDGES 100000
#define E_PAD   100032   // 1563 * 64

typedef __attribute__((ext_vector_type(8))) short bf16x8;
typedef __attribute__((ext_vector_type(4))) float f32x4;

__device__ __forceinline__ void gload_lds16(const void* g, void* l) {
  __builtin_amdgcn_global_load_lds(
      (const __attribute__((address_space(1))) unsigned int*)g,
      (__attribute__((address_space(3))) unsigned int*)l, 16, 0, 0);
}

__device__ __forceinline__ unsigned short f2bf(float v) {
  __hip_bfloat16 hb = __float2bfloat16(v);
  return *reinterpret_cast<unsigned short*>(&hb);
}

__device__ __forceinline__ unsigned fkey(float f) {
  unsigned u = __float_as_uint(f);
  return (u & 0x80000000u) ? ~u : (u | 0x80000000u);
}
__device__ __forceinline__ float fdec(unsigned k) {
  return (k & 0x80000000u) ? __uint_as_float(k ^ 0x80000000u) : __uint_as_float(~k);
}

// h = relu(e @ W1 + b1), bf16, written DIRECTLY in MFMA A-fragment order:
// thread g stores 16B at g*16 (perfectly coalesced). Fragment f=g>>6, lane=g&63:
// holds h[e = (f>>4)*64 + ((f>>2)&3)*16 + (lane&15)][k0 = (f&3)*32 + (lane>>4)*8 .. +8]
__global__ __launch_bounds__(256) void k_h(const float* __restrict__ ef,
    const float* __restrict__ W1, const float* __restrict__ b1,
    unsigned char* __restrict__ hfr) {
  int g = blockIdx.x * 256 + threadIdx.x;          // E_PAD*16 threads
  int lane = g & 63, f = g >> 6;
  int e = (f >> 4) * 64 + ((f >> 2) & 3) * 16 + (lane & 15);
  int k0 = (f & 3) * 32 + ((lane >> 4) & 3) * 8;
  bf16x8 v;
  if (e < N_EDGES) {
    f32x4 acc0 = *(const f32x4*)(b1 + k0);
    f32x4 acc1 = *(const f32x4*)(b1 + k0 + 4);
    const float* er = ef + (size_t)e * 16;
    #pragma unroll
    for (int j = 0; j < 16; ++j) {
      float ev = er[j];
      f32x4 w0 = *(const f32x4*)(W1 + j * 128 + k0);
      f32x4 w1 = *(const f32x4*)(W1 + j * 128 + k0 + 4);
      #pragma unroll
      for (int r = 0; r < 4; ++r) { acc0[r] += ev * w0[r]; acc1[r] += ev * w1[r]; }
    }
    #pragma unroll
    for (int r = 0; r < 4; ++r) {
      v[r]     = (short)f2bf(acc0[r] > 0.f ? acc0[r] : 0.f);
      v[r + 4] = (short)f2bf(acc1[r] > 0.f ? acc1[r] : 0.f);
    }
  } else {
    #pragma unroll
    for (int r = 0; r < 8; ++r) v[r] = 0;
  }
  *(bf16x8*)(hfr + (size_t)g * 16) = v;
}

// W2 -> bf16 packed in per-(chunk i, wave w, lane, s) MFMA B-fragment order:
// 16B frag at ((i*4+w)*64+lane)*64 + s*16 holds W2[k0..k0+8][i*64 + w*16 + (lane&15)]
// with k0 = s*32 + (lane>>4)*8.
__global__ __launch_bounds__(256) void k_w2pk(const float* __restrict__ W2,
    unsigned char* __restrict__ out) {
  int g = blockIdx.x * 256 + threadIdx.x;          // 32768 threads
  int s = g & 3, lane = (g >> 2) & 63, w = (g >> 8) & 3, i = g >> 10;
  int col = i * 64 + w * 16 + (lane & 15);
  int k0 = s * 32 + (lane >> 4) * 8;
  bf16x8 v;
  #pragma unroll
  for (int j = 0; j < 8; ++j)
    v[j] = (short)f2bf(W2[(size_t)(k0 + j) * 2048 + col]);
  *(bf16x8*)(out + (size_t)g * 16) = v;
}

// Fused node-side prep: out = bias + x@root; xb = x@b2' ; ab1/ab2 ; mk/s init.
__global__ __launch_bounds__(256) void k_pre(const float* __restrict__ x,
    const float* __restrict__ root, const float* __restrict__ b2,
    const float* __restrict__ att, const float* __restrict__ bias,
    float* __restrict__ out, float* __restrict__ xb,
    float* __restrict__ ab1, float* __restrict__ ab2,
    unsigned* __restrict__ mk, float* __restrict__ s_sum) {
  __shared__ float lxb[4][64];
  int g = blockIdx.x * 256 + threadIdx.x;          // N*64 exact
  int n = g >> 6, o = g & 63;
  const float* xr = x + (size_t)n * 32;
  float ra = bias[o], xa = 0.f;
  #pragma unroll
  for (int i = 0; i < 32; ++i) {
    float xv = xr[i];
    ra += xv * root[i * 64 + o];
    xa += xv * b2[i * 64 + o];
  }
  out[g] = ra;
  xb[g] = xa;
  int ln = threadIdx.x >> 6;
  lxb[ln][o] = xa;
  __syncthreads();
  if (o < 8) {
    int hd = o;
    float s1 = 0.f, s2 = 0.f;
    #pragma unroll
    for (int c = 0; c < 8; ++c) {
      float v = lxb[ln][hd * 8 + c];
      s1 += v * att[hd * 16 + c];
      s2 += v * att[hd * 16 + 8 + c];
    }
    size_t idx = (size_t)n * 8 + hd;
    ab1[idx] = s1; ab2[idx] = s2; mk[idx] = 0u; s_sum[idx] = 0.f;
  }
}

// R6 structure + 1-pair-deep register software pipeline for B-fragments.
// A-fragments in LDS (linear frag order, conflict-free), re-read per pair per
// mt. B loads for pair p+1 issue BEFORE pair p's MFMA cluster; the "+v" pin
// sits AFTER the cluster so the vmcnt wait lands post-compute. No barriers in
// the K-loop.
__global__ __launch_bounds__(256)
__attribute__((amdgpu_waves_per_eu(2, 5)))
void k_main(
    const float* __restrict__ x, const int* __restrict__ ei,
    const float* __restrict__ att, const float* __restrict__ ab1,
    const float* __restrict__ ab2, const unsigned char* __restrict__ hfr,
    const unsigned char* __restrict__ w2pk,
    float* __restrict__ xj_out, float* __restrict__ alpha_out,
    unsigned* __restrict__ mk) {
  __shared__ unsigned char lds_h[16384];   // 16 frags x 64 lanes x 16B, linear
  __shared__ float lds_xs[32 * 64];        // [ch][edge] x[src] transposed
  __shared__ float lds_xd[32 * 64];        // [ch][edge] x[dst] transposed
  const int tid = threadIdx.x;
  const int lane = tid & 63;
  const int w = tid >> 6;                  // wave id: owns output cols w*16..+15
  const int e0 = blockIdx.x * 64;
  const int* srcp = ei;
  const int* dstp = ei + N_EDGES;

  // stage h fragments (linear dest = linear source, 4 gload per wave)
  const unsigned char* hp = hfr + (size_t)blockIdx.x * 16384;
  #pragma unroll
  for (int r = 0; r < 4; ++r)
    gload_lds16(hp + (w * 4 + r) * 1024 + lane * 16, lds_h + (w * 4 + r) * 1024);

  // gather x rows for src/dst (transposed into LDS)
  {
    int m = tid & 63;
    int half = (tid >> 6) & 1;
    int which = tid >> 7;
    int eIdx = e0 + m; if (eIdx >= N_EDGES) eIdx = N_EDGES - 1;
    int node = which ? dstp[eIdx] : srcp[eIdx];
    const f32x4* xr = (const f32x4*)(x + (size_t)node * 32 + half * 16);
    float* lx = which ? lds_xd : lds_xs;
    #pragma unroll
    for (int q = 0; q < 4; ++q) {
      f32x4 vv = xr[q];
      int i0 = half * 16 + q * 4;
      #pragma unroll
      for (int j = 0; j < 4; ++j) lx[(i0 + j) * 64 + m] = vv[j];
    }
  }
  __syncthreads();

  const unsigned char* bgp = w2pk + (size_t)w * 4096 + (size_t)lane * 64;
  f32x4 xj_acc[4] = {};
  f32x4 xi_acc[4] = {};
  const int rg4 = ((lane >> 4) & 3) * 4;
  const int lb16 = lane * 16;

  // pipeline register sets: P = even pair, Q = odd pair (static indexing)
  bf16x8 pA0[4], pB0[4], pA1[4], pB1[4];
  #pragma unroll
  for (int s = 0; s < 4; ++s) {
    pA0[s] = *(const bf16x8*)(bgp + (size_t)0 * 16384 + s * 16);   // chunk 0
    pB0[s] = *(const bf16x8*)(bgp + (size_t)1 * 16384 + s * 16);   // chunk 1
  }

  #pragma unroll 1
  for (int it = 0; it < 8; ++it) {
    const int i = it * 4;
    // issue loads for pair 2 (chunks i+2, i+3) into set 1
    #pragma unroll
    for (int s = 0; s < 4; ++s) {
      pA1[s] = *(const bf16x8*)(bgp + (size_t)(i + 2) * 16384 + s * 16);
      pB1[s] = *(const bf16x8*)(bgp + (size_t)(i + 3) * 16384 + s * 16);
    }
    // compute chunks i, i+1 from set 0
    __builtin_amdgcn_s_setprio(1);
    #pragma unroll
    for (int mt = 0; mt < 4; ++mt) {
      f32x4 gA = {0.f, 0.f, 0.f, 0.f};
      f32x4 gB = {0.f, 0.f, 0.f, 0.f};
      #pragma unroll
      for (int s = 0; s < 4; ++s) {
        bf16x8 a = *(const bf16x8*)(lds_h + (mt * 4 + s) * 1024 + lb16);
        gA = __builtin_amdgcn_mfma_f32_16x16x32_bf16(a, pA0[s], gA, 0, 0, 0);
        gB = __builtin_amdgcn_mfma_f32_16x16x32_bf16(a, pB0[s], gB, 0, 0, 0);
      }
      f32x4 xsv0 = *(const f32x4*)(lds_xs + i * 64 + mt * 16 + rg4);
      f32x4 xdv0 = *(const f32x4*)(lds_xd + i * 64 + mt * 16 + rg4);
      f32x4 xsv1 = *(const f32x4*)(lds_xs + (i + 1) * 64 + mt * 16 + rg4);
      f32x4 xdv1 = *(const f32x4*)(lds_xd + (i + 1) * 64 + mt * 16 + rg4);
      #pragma unroll
      for (int r = 0; r < 4; ++r) {
        xj_acc[mt][r] += xsv0[r] * gA[r] + xsv1[r] * gB[r];
        xi_acc[mt][r] += xdv0[r] * gA[r] + xdv1[r] * gB[r];
      }
    }
    __builtin_amdgcn_s_setprio(0);
    // set-1 loads completed during compute; pin here (wait lands post-MFMA)
    #pragma unroll
    for (int s = 0; s < 4; ++s) {
      asm volatile("" : "+v"(pA1[s]));
      asm volatile("" : "+v"(pB1[s]));
    }
    // issue loads for next iteration's pair 1 (chunks i+4, i+5) into set 0
    {
      const int i4 = (i + 4) & 31;
      const int i5 = (i + 5) & 31;
      #pragma unroll
      for (int s = 0; s < 4; ++s) {
        pA0[s] = *(const bf16x8*)(bgp + (size_t)i4 * 16384 + s * 16);
        pB0[s] = *(const bf16x8*)(bgp + (size_t)i5 * 16384 + s * 16);
      }
    }
    // compute chunks i+2, i+3 from set 1
    __builtin_amdgcn_s_setprio(1);
    #pragma unroll
    for (int mt = 0; mt < 4; ++mt) {
      f32x4 gA = {0.f, 0.f, 0.f, 0.f};
      f32x4 gB = {0.f, 0.f, 0.f, 0.f};
      #pragma unroll
      for (int s = 0; s < 4; ++s) {
        bf16x8 a = *(const bf16x8*)(lds_h + (mt * 4 + s) * 1024 + lb16);
        gA = __builtin_amdgcn_mfma_f32_16x16x32_bf16(a, pA1[s], gA, 0, 0, 0);
        gB = __builtin_amdgcn_mfma_f32_16x16x32_bf16(a, pB1[s], gB, 0, 0, 0);
      }
      f32x4 xsv0 = *(const f32x4*)(lds_xs + (i + 2) * 64 + mt * 16 + rg4);
      f32x4 xdv0 = *(const f32x4*)(lds_xd + (i + 2) * 64 + mt * 16 + rg4);
      f32x4 xsv1 = *(const f32x4*)(lds_xs + (i + 3) * 64 + mt * 16 + rg4);
      f32x4 xdv1 = *(const f32x4*)(lds_xd + (i + 3) * 64 + mt * 16 + rg4);
      #pragma unroll
      for (int r = 0; r < 4; ++r) {
        xj_acc[mt][r] += xsv0[r] * gA[r] + xsv1[r] * gB[r];
        xi_acc[mt][r] += xdv0[r] * gA[r] + xdv1[r] * gB[r];
      }
    }
    __builtin_amdgcn_s_setprio(0);
    // pin set 0 (its wait lands after this pair's MFMAs)
    #pragma unroll
    for (int s = 0; s < 4; ++s) {
      asm volatile("" : "+v"(pA0[s]));
      asm volatile("" : "+v"(pB0[s]));
    }
  }

  // epilogue: store xj, attention logits (reduce 8 channels/head), fused atomicMax
  const int h2 = (lane >> 3) & 1;
  const int cc = lane & 7;
  const int head = 2 * w + h2;
  const float a1v = att[head * 16 + cc];
  const float a2v = att[head * 16 + 8 + cc];
  #pragma unroll
  for (int mt = 0; mt < 4; ++mt) {
    #pragma unroll
    for (int r = 0; r < 4; ++r) {
      int row = mt * 16 + rg4 + r;
      int eIdx = e0 + row;
      xj_out[(size_t)eIdx * 64 + w * 16 + (lane & 15)] = xj_acc[mt][r];
      float v = xi_acc[mt][r] * a1v + xj_acc[mt][r] * a2v;
      v += __shfl_xor(v, 1);
      v += __shfl_xor(v, 2);
      v += __shfl_xor(v, 4);
      if (cc == 0 && eIdx < N_EDGES) {
        int d = dstp[eIdx];
        float lg = v + ab1[(size_t)d * 8 + head] + ab2[(size_t)srcp[eIdx] * 8 + head];
        lg = lg > 0.f ? lg : 0.2f * lg;
        alpha_out[(size_t)eIdx * 8 + head] = lg;
        atomicMax(mk + (size_t)d * 8 + head, fkey(lg));
      }
    }
  }
}

__global__ __launch_bounds__(256) void k_exp(float* __restrict__ alpha,
    const int* __restrict__ ei, const unsigned* __restrict__ mk, float* __restrict__ s) {
  int g = blockIdx.x * 256 + threadIdx.x;          // E*8 exact
  int e = g >> 3, hd = g & 7;
  int d = ei[N_EDGES + e];
  float ea = expf(alpha[g] - fdec(mk[(size_t)d * 8 + hd]));
  alpha[g] = ea;
  atomicAdd(s + (size_t)d * 8 + hd, ea);
}

__global__ __launch_bounds__(256) void k_scatter(const float* __restrict__ xj,
    const float* __restrict__ xb, const float* __restrict__ alpha,
    const float* __restrict__ s, const int* __restrict__ ei,
    const float* __restrict__ bias, float* __restrict__ out) {
  int g = blockIdx.x * 256 + threadIdx.x;          // E*64 exact
  int e = g >> 6, o = g & 63, hd = o >> 3;
  int sidx = ei[e], d = ei[N_EDGES + e];
  float ea = alpha[(size_t)e * 8 + hd];
  float sv = s[(size_t)d * 8 + hd];
  float val = (xj[g] + xb[(size_t)sidx * 64 + o]) * (ea / (sv + 1e-16f)) + bias[o];
  atomicAdd(out + (size_t)d * 64 + o, val);
}

__global__ __launch_bounds__(256) void k_elu(float* __restrict__ out) {
  int g = blockIdx.x * 256 + threadIdx.x;          // N*64 exact
  float v = out[g];
  out[g] = v > 0.f ? v : expm1f(v);
}

extern "C" void kernel_launch(void* const* d_in, const int* in_sizes, int n_in,
                              void* d_out, int out_size, void* d_ws, size_t ws_size,
                              hipStream_t stream) {
  const float* x    = (const float*)d_in[0];
  const int*   eidx = (const int*)d_in[1];
  const float* ef   = (const float*)d_in[2];
  const float* W1   = (const float*)d_in[3];
  const float* b1   = (const float*)d_in[4];
  const float* W2   = (const float*)d_in[5];
  const float* b2   = (const float*)d_in[6];
  const float* att  = (const float*)d_in[7];
  const float* bias = (const float*)d_in[8];
  const float* root = (const float*)d_in[9];
  float* out = (float*)d_out;
  char* ws = (char*)d_ws;

  // workspace layout (all 256B aligned), total ~64.5 MB
  unsigned char* h_fr  = (unsigned char*)(ws + 0);          // E_PAD*128 bf16 = 25,608,192
  unsigned char* w2pk  = (unsigned char*)(ws + 25608192);   // 512 KB packed B-fragments
  float* xb    = (float*)(ws + 26132480);                   // N*64 f32
  float* ab1   = (float*)(ws + 32532480);                   // N*8 f32
  float* ab2   = (float*)(ws + 33332480);                   // N*8 f32
  float* xj_ws = (float*)(ws + 34132480);                   // E_PAD*64 f32
  float* al_ws = (float*)(ws + 59740672);                   // E_PAD*8 f32
  unsigned* mk = (unsigned*)(ws + 62941696);                // N*8 u32
  float* s_sum = (float*)(ws + 63741696);                   // N*8 f32

  k_h    <<<E_PAD * 16 / 256, 256, 0, stream>>>(ef, W1, b1, h_fr);
  k_w2pk <<<128, 256, 0, stream>>>(W2, w2pk);
  k_pre  <<<N_NODES * 64 / 256, 256, 0, stream>>>(x, root, b2, att, bias,
                                                  out, xb, ab1, ab2, mk, s_sum);
  k_main <<<E_PAD / 64, 256, 0, stream>>>(x, eidx, att, ab1, ab2, h_fr, w2pk,
                                          xj_ws, al_ws, mk);
  k_exp  <<<N_EDGES * 8 / 256, 256, 0, stream>>>(al_ws, eidx, mk, s_sum);
  k_scatter<<<N_EDGES * 64 / 256, 256, 0, stream>>>(xj_ws, xb, al_ws, s_sum, eidx, bias, out);
  k_elu  <<<N_NODES * 64 / 256, 256, 0, stream>>>(out);
}

// Round 10
// 196.814 us; speedup vs baseline: 1.1922x; 1.0660x over previous
//
#include <hip/hip_runtime.h>
#include <hip/hip_bf16.h>

#define N_NODES 25000
#define N_EDGES 100000
#define E_PAD   100032   // 1563 * 64

typedef __attribute__((ext_vector_type(8))) short bf16x8;
typedef __attribute__((ext_vector_type(4))) float f32x4;
typedef __attribute__((ext_vector_type(4))) unsigned short u16x4;

__device__ __forceinline__ unsigned short f2bf(float v) {
  __hip_bfloat16 hb = __float2bfloat16(v);
  return *reinterpret_cast<unsigned short*>(&hb);
}
__device__ __forceinline__ float bf2f(unsigned short u) {
  return __uint_as_float(((unsigned)u) << 16);
}

__device__ __forceinline__ unsigned fkey(float f) {
  unsigned u = __float_as_uint(f);
  return (u & 0x80000000u) ? ~u : (u | 0x80000000u);
}
__device__ __forceinline__ float fdec(unsigned k) {
  return (k & 0x80000000u) ? __uint_as_float(k ^ 0x80000000u) : __uint_as_float(~k);
}

// W2 -> bf16 packed in per-(chunk i, wave w, lane, s) MFMA B-fragment order:
// 16B frag at ((i*4+w)*64+lane)*64 + s*16 holds W2[k0..k0+8][i*64 + w*16 + (lane&15)]
// with k0 = s*32 + (lane>>4)*8.
__global__ __launch_bounds__(256) void k_w2pk(const float* __restrict__ W2,
    unsigned char* __restrict__ out) {
  int g = blockIdx.x * 256 + threadIdx.x;          // 32768 threads
  int s = g & 3, lane = (g >> 2) & 63, w = (g >> 8) & 3, i = g >> 10;
  int col = i * 64 + w * 16 + (lane & 15);
  int k0 = s * 32 + (lane >> 4) * 8;
  bf16x8 v;
  #pragma unroll
  for (int j = 0; j < 8; ++j)
    v[j] = (short)f2bf(W2[(size_t)(k0 + j) * 2048 + col]);
  *(bf16x8*)(out + (size_t)g * 16) = v;
}

// Fused node-side prep: out = bias + x@root; xb = x@b2' ; ab1/ab2 ; mk/s init.
__global__ __launch_bounds__(256) void k_pre(const float* __restrict__ x,
    const float* __restrict__ root, const float* __restrict__ b2,
    const float* __restrict__ att, const float* __restrict__ bias,
    float* __restrict__ out, float* __restrict__ xb,
    float* __restrict__ ab1, float* __restrict__ ab2,
    unsigned* __restrict__ mk, float* __restrict__ s_sum) {
  __shared__ float lxb[4][64];
  int g = blockIdx.x * 256 + threadIdx.x;          // N*64 exact
  int n = g >> 6, o = g & 63;
  const float* xr = x + (size_t)n * 32;
  float ra = bias[o], xa = 0.f;
  #pragma unroll
  for (int i = 0; i < 32; ++i) {
    float xv = xr[i];
    ra += xv * root[i * 64 + o];
    xa += xv * b2[i * 64 + o];
  }
  out[g] = ra;
  xb[g] = xa;
  int ln = threadIdx.x >> 6;
  lxb[ln][o] = xa;
  __syncthreads();
  if (o < 8) {
    int hd = o;
    float s1 = 0.f, s2 = 0.f;
    #pragma unroll
    for (int c = 0; c < 8; ++c) {
      float v = lxb[ln][hd * 8 + c];
      s1 += v * att[hd * 16 + c];
      s2 += v * att[hd * 16 + 8 + c];
    }
    size_t idx = (size_t)n * 8 + hd;
    ab1[idx] = s1; ab2[idx] = s2; mk[idx] = 0u; s_sum[idx] = 0.f;
  }
}

// R6 structure with h computed INLINE (no k_h kernel, no hfr HBM round-trip):
// prologue computes h = relu(ef@W1+b1) for the block's 64 edges straight into
// fragment-ordered LDS via ds_write_b128 (conflict-free). xs/xd stored bf16
// (LDS 24 KB total). K-loop identical to R6: B-fragments direct from
// L2-resident packed W2, register double-buffer, no barriers.
__global__ __launch_bounds__(256)
__attribute__((amdgpu_waves_per_eu(2, 5)))
void k_main(
    const float* __restrict__ x, const int* __restrict__ ei,
    const float* __restrict__ ef, const float* __restrict__ W1,
    const float* __restrict__ b1,
    const float* __restrict__ att, const float* __restrict__ ab1,
    const float* __restrict__ ab2,
    const unsigned char* __restrict__ w2pk,
    float* __restrict__ xj_out, float* __restrict__ alpha_out,
    unsigned* __restrict__ mk) {
  __shared__ unsigned char lds_h[16384];       // 16 frags x 64 lanes x 16B, linear
  __shared__ unsigned short lds_x[2][32][64];  // [src/dst][ch][edge] bf16, 8 KB
  const int tid = threadIdx.x;
  const int lane = tid & 63;
  const int w = tid >> 6;                      // wave id: owns output cols w*16..+15
  const int e0 = blockIdx.x * 64;
  const int* srcp = ei;
  const int* dstp = ei + N_EDGES;

  // ---- inline h: wave w computes row-block mt=w's 4 K-step fragments ----
  // thread covers edge e0 + w*16 + (lane&15), k = r*32 + (lane>>4)*8 .. +8
  {
    int eIdx = e0 + w * 16 + (lane & 15);
    bool valid = eIdx < N_EDGES;
    const float* er = ef + (size_t)(valid ? eIdx : 0) * 16;
    float efr[16];
    #pragma unroll
    for (int q = 0; q < 4; ++q) {
      f32x4 vv = *(const f32x4*)(er + q * 4);
      #pragma unroll
      for (int j = 0; j < 4; ++j) efr[q * 4 + j] = vv[j];
    }
    #pragma unroll
    for (int r = 0; r < 4; ++r) {
      int k0 = r * 32 + ((lane >> 4) & 3) * 8;
      f32x4 acc0 = *(const f32x4*)(b1 + k0);
      f32x4 acc1 = *(const f32x4*)(b1 + k0 + 4);
      #pragma unroll
      for (int j = 0; j < 16; ++j) {
        float ev = efr[j];
        f32x4 w0 = *(const f32x4*)(W1 + j * 128 + k0);
        f32x4 w1 = *(const f32x4*)(W1 + j * 128 + k0 + 4);
        #pragma unroll
        for (int t = 0; t < 4; ++t) { acc0[t] += ev * w0[t]; acc1[t] += ev * w1[t]; }
      }
      bf16x8 v;
      #pragma unroll
      for (int t = 0; t < 4; ++t) {
        float a0 = (valid && acc0[t] > 0.f) ? acc0[t] : 0.f;
        float a1 = (valid && acc1[t] > 0.f) ? acc1[t] : 0.f;
        v[t]     = (short)f2bf(a0);
        v[t + 4] = (short)f2bf(a1);
      }
      *(bf16x8*)(lds_h + (w * 4 + r) * 1024 + lane * 16) = v;
    }
  }

  // ---- gather x rows for src/dst -> bf16 transposed LDS ----
  {
    int m = tid & 63;
    int half = (tid >> 6) & 1;
    int which = tid >> 7;
    int eIdx = e0 + m; if (eIdx >= N_EDGES) eIdx = N_EDGES - 1;
    int node = which ? dstp[eIdx] : srcp[eIdx];
    const f32x4* xr = (const f32x4*)(x + (size_t)node * 32 + half * 16);
    #pragma unroll
    for (int q = 0; q < 4; ++q) {
      f32x4 vv = xr[q];
      #pragma unroll
      for (int j = 0; j < 4; ++j)
        lds_x[which][half * 16 + q * 4 + j][m] = f2bf(vv[j]);
    }
  }
  __syncthreads();

  // ---- K-loop (identical to R6) ----
  const unsigned char* bgp = w2pk + (size_t)w * 4096 + (size_t)lane * 64;
  bf16x8 bA[4], bB[4];
  #pragma unroll
  for (int s = 0; s < 4; ++s) bA[s] = *(const bf16x8*)(bgp + s * 16);

  f32x4 xj_acc[4] = {};
  f32x4 xi_acc[4] = {};
  const int rg4 = ((lane >> 4) & 3) * 4;
  const int lb16 = lane * 16;

  #pragma unroll 1
  for (int i = 0; i < 32; i += 2) {
    // prefetch chunk i+1 into bB
    #pragma unroll
    for (int s = 0; s < 4; ++s)
      bB[s] = *(const bf16x8*)(bgp + (size_t)(i + 1) * 16384 + s * 16);
    // compute chunk i from bA
    __builtin_amdgcn_s_setprio(1);
    #pragma unroll
    for (int mt = 0; mt < 4; ++mt) {
      f32x4 g = {0.f, 0.f, 0.f, 0.f};
      #pragma unroll
      for (int s = 0; s < 4; ++s) {
        bf16x8 a = *(const bf16x8*)(lds_h + (mt * 4 + s) * 1024 + lb16);
        g = __builtin_amdgcn_mfma_f32_16x16x32_bf16(a, bA[s], g, 0, 0, 0);
      }
      u16x4 xsh = *(const u16x4*)&lds_x[0][i][mt * 16 + rg4];
      u16x4 xdh = *(const u16x4*)&lds_x[1][i][mt * 16 + rg4];
      #pragma unroll
      for (int r = 0; r < 4; ++r) {
        xj_acc[mt][r] += bf2f(xsh[r]) * g[r];
        xi_acc[mt][r] += bf2f(xdh[r]) * g[r];
      }
    }
    __builtin_amdgcn_s_setprio(0);
    // prefetch chunk i+2 into bA (wraps harmlessly on last iter)
    {
      int inx = (i + 2) & 31;
      #pragma unroll
      for (int s = 0; s < 4; ++s)
        bA[s] = *(const bf16x8*)(bgp + (size_t)inx * 16384 + s * 16);
    }
    // compute chunk i+1 from bB
    __builtin_amdgcn_s_setprio(1);
    #pragma unroll
    for (int mt = 0; mt < 4; ++mt) {
      f32x4 g = {0.f, 0.f, 0.f, 0.f};
      #pragma unroll
      for (int s = 0; s < 4; ++s) {
        bf16x8 a = *(const bf16x8*)(lds_h + (mt * 4 + s) * 1024 + lb16);
        g = __builtin_amdgcn_mfma_f32_16x16x32_bf16(a, bB[s], g, 0, 0, 0);
      }
      u16x4 xsh = *(const u16x4*)&lds_x[0][i + 1][mt * 16 + rg4];
      u16x4 xdh = *(const u16x4*)&lds_x[1][i + 1][mt * 16 + rg4];
      #pragma unroll
      for (int r = 0; r < 4; ++r) {
        xj_acc[mt][r] += bf2f(xsh[r]) * g[r];
        xi_acc[mt][r] += bf2f(xdh[r]) * g[r];
      }
    }
    __builtin_amdgcn_s_setprio(0);
  }

  // ---- epilogue: xj stores, attention logits, fused atomicMax ----
  const int h2 = (lane >> 3) & 1;
  const int cc = lane & 7;
  const int head = 2 * w + h2;
  const float a1v = att[head * 16 + cc];
  const float a2v = att[head * 16 + 8 + cc];
  #pragma unroll
  for (int mt = 0; mt < 4; ++mt) {
    #pragma unroll
    for (int r = 0; r < 4; ++r) {
      int row = mt * 16 + rg4 + r;
      int eIdx = e0 + row;
      xj_out[(size_t)eIdx * 64 + w * 16 + (lane & 15)] = xj_acc[mt][r];
      float v = xi_acc[mt][r] * a1v + xj_acc[mt][r] * a2v;
      v += __shfl_xor(v, 1);
      v += __shfl_xor(v, 2);
      v += __shfl_xor(v, 4);
      if (cc == 0 && eIdx < N_EDGES) {
        int d = dstp[eIdx];
        float lg = v + ab1[(size_t)d * 8 + head] + ab2[(size_t)srcp[eIdx] * 8 + head];
        lg = lg > 0.f ? lg : 0.2f * lg;
        alpha_out[(size_t)eIdx * 8 + head] = lg;
        atomicMax(mk + (size_t)d * 8 + head, fkey(lg));
      }
    }
  }
}

__global__ __launch_bounds__(256) void k_exp(float* __restrict__ alpha,
    const int* __restrict__ ei, const unsigned* __restrict__ mk, float* __restrict__ s) {
  int g = blockIdx.x * 256 + threadIdx.x;          // E*8 exact
  int e = g >> 3, hd = g & 7;
  int d = ei[N_EDGES + e];
  float ea = expf(alpha[g] - fdec(mk[(size_t)d * 8 + hd]));
  alpha[g] = ea;
  atomicAdd(s + (size_t)d * 8 + hd, ea);
}

__global__ __launch_bounds__(256) void k_scatter(const float* __restrict__ xj,
    const float* __restrict__ xb, const float* __restrict__ alpha,
    const float* __restrict__ s, const int* __restrict__ ei,
    const float* __restrict__ bias, float* __restrict__ out) {
  int g = blockIdx.x * 256 + threadIdx.x;          // E*64 exact
  int e = g >> 6, o = g & 63, hd = o >> 3;
  int sidx = ei[e], d = ei[N_EDGES + e];
  float ea = alpha[(size_t)e * 8 + hd];
  float sv = s[(size_t)d * 8 + hd];
  float val = (xj[g] + xb[(size_t)sidx * 64 + o]) * (ea / (sv + 1e-16f)) + bias[o];
  atomicAdd(out + (size_t)d * 64 + o, val);
}

__global__ __launch_bounds__(256) void k_elu(float* __restrict__ out) {
  int g = blockIdx.x * 256 + threadIdx.x;          // N*64 exact
  float v = out[g];
  out[g] = v > 0.f ? v : expm1f(v);
}

extern "C" void kernel_launch(void* const* d_in, const int* in_sizes, int n_in,
                              void* d_out, int out_size, void* d_ws, size_t ws_size,
                              hipStream_t stream) {
  const float* x    = (const float*)d_in[0];
  const int*   eidx = (const int*)d_in[1];
  const float* ef   = (const float*)d_in[2];
  const float* W1   = (const float*)d_in[3];
  const float* b1   = (const float*)d_in[4];
  const float* W2   = (const float*)d_in[5];
  const float* b2   = (const float*)d_in[6];
  const float* att  = (const float*)d_in[7];
  const float* bias = (const float*)d_in[8];
  const float* root = (const float*)d_in[9];
  float* out = (float*)d_out;
  char* ws = (char*)d_ws;

  // workspace layout (256B aligned), total ~39 MB
  unsigned char* w2pk = (unsigned char*)(ws + 0);           // 512 KB packed B-frags
  float* xb    = (float*)(ws + 524288);                     // N*64 f32
  float* ab1   = (float*)(ws + 6924288);                    // N*8 f32
  float* ab2   = (float*)(ws + 7724288);                    // N*8 f32
  float* xj_ws = (float*)(ws + 8524288);                    // E_PAD*64 f32
  float* al_ws = (float*)(ws + 34132480);                   // E_PAD*8 f32
  unsigned* mk = (unsigned*)(ws + 37333504);                // N*8 u32
  float* s_sum = (float*)(ws + 38133504);                   // N*8 f32

  k_w2pk <<<128, 256, 0, stream>>>(W2, w2pk);
  k_pre  <<<N_NODES * 64 / 256, 256, 0, stream>>>(x, root, b2, att, bias,
                                                  out, xb, ab1, ab2, mk, s_sum);
  k_main <<<E_PAD / 64, 256, 0, stream>>>(x, eidx, ef, W1, b1, att, ab1, ab2,
                                          w2pk, xj_ws, al_ws, mk);
  k_exp  <<<N_EDGES * 8 / 256, 256, 0, stream>>>(al_ws, eidx, mk, s_sum);
  k_scatter<<<N_EDGES * 64 / 256, 256, 0, stream>>>(xj_ws, xb, al_ws, s_sum, eidx, bias, out);
  k_elu  <<<N_NODES * 64 / 256, 256, 0, stream>>>(out);
}